// Round 8
// baseline (410.416 us; speedup 1.0000x reference)
//
#include <hip/hip_runtime.h>
#include <math.h>

#define N_B 2
#define HH 48
#define WW 48
#define DM 256
#define NH 4
#define EH 64
#define KS 7
#define NPIX (N_B*HH*WW)    // 4608
#define GRID 512            // 2 blocks/CU x 256 CUs; LDS 59.4KB caps HW at 2/CU, launch_bounds caps VGPR

typedef _Float16 half8 __attribute__((ext_vector_type(8)));
typedef float float4v __attribute__((ext_vector_type(4)));

// Software global barrier: all GRID blocks are co-resident (see capacity argument above).
// Release-add + acquire-spin at device (AGENT) scope, threadfence for L2 writeback/invalidate.
#define GBAR(idx) do { \
    __syncthreads(); \
    if (t == 0) { \
        __threadfence(); \
        __hip_atomic_fetch_add(&cnt[idx], 1, __ATOMIC_RELEASE, __HIP_MEMORY_SCOPE_AGENT); \
        while (__hip_atomic_load(&cnt[idx], __ATOMIC_ACQUIRE, __HIP_MEMORY_SCOPE_AGENT) < (int)gridDim.x) \
            __builtin_amdgcn_s_sleep(1); \
        __threadfence(); \
    } \
    __syncthreads(); \
} while (0)

__global__ __launch_bounds__(256, 2) void mega(const float* __restrict__ x,
                                               const float* __restrict__ pos,
                                               const float* __restrict__ cond,
                                               const float* __restrict__ w_norm,
                                               const float* __restrict__ w_qkv,
                                               const float* __restrict__ w_out,
                                               float* __restrict__ out,
                                               int* __restrict__ cnt,
                                               float* __restrict__ scale,
                                               _Float16* __restrict__ xn,
                                               _Float16* __restrict__ qh,
                                               _Float16* __restrict__ kh,
                                               _Float16* __restrict__ vh,
                                               _Float16* __restrict__ obuf) {
    int bid = blockIdx.x, nblk = gridDim.x;
    int t = threadIdx.x;
    int wave = t >> 6, lane = t & 63;

    __shared__ union {
        struct { _Float16 As[64*40]; _Float16 Bs[64*40]; } g;          // gemm phases (10 KB)
        struct { _Float16 VT[64*232]; _Float16 SP[64*232]; } at;       // attn phase (59.4 KB)
        float wsum[4];                                                  // rmsnorm phase
    } sm;

    // ================= Phase 0: scale = cond @ w_norm.T + 1 (blocks 0..15) =================
    if (bid < 16) {
        int b = bid & 1, yg = bid >> 1;
        int d = yg*32 + wave*8 + (lane >> 3);
        int l8 = lane & 7;
        const float4* wr4 = (const float4*)(w_norm + (size_t)d*DM) + l8*8;
        const float4* c4  = (const float4*)(cond + (size_t)b*DM) + l8*8;
        float acc = 0.f;
        #pragma unroll
        for (int j = 0; j < 8; ++j) {
            float4 w = wr4[j], c = c4[j];
            acc += w.x*c.x + w.y*c.y + w.z*c.z + w.w*c.w;
        }
        acc += __shfl_xor(acc, 1, 64);
        acc += __shfl_xor(acc, 2, 64);
        acc += __shfl_xor(acc, 4, 64);
        if (l8 == 0) scale[b*DM + d] = acc + 1.0f;
    }
    GBAR(0);

    // ================= Phase 1: RMSNorm -> fp16 xn =================
    for (int pix = bid; pix < NPIX; pix += nblk) {
        int b = pix / (HH*WW);
        float v = x[(size_t)pix*DM + t];
        float ss = v*v;
        #pragma unroll
        for (int off = 32; off > 0; off >>= 1) ss += __shfl_xor(ss, off, 64);
        if ((t & 63) == 0) sm.wsum[t>>6] = ss;
        __syncthreads();
        float tot = sm.wsum[0]+sm.wsum[1]+sm.wsum[2]+sm.wsum[3];
        float r = rsqrtf(tot*(1.0f/DM) + 1e-6f);
        xn[(size_t)pix*DM + t] = (_Float16)(v * scale[b*DM + t] * r);
        __syncthreads();   // protect wsum for next loop iter
    }
    GBAR(1);

    // ================= Phase 2: QKV GEMM (fp16 MFMA) + fused RoPE (864 tiles) =================
    {
        const int K = DM, LDT = 40;
        int lr = t >> 2, lk = (t & 3) * 8;
        int frow = lane & 15, kq = (lane >> 4) * 8;
        int col = lane & 15, rbase = (lane >> 4) * 4;
        float freq = __expf(1.14472988585f + (float)(col & 7) * 0.287823136624f); // pi * 10^(mf/8)
        for (int tile = bid; tile < 72*12; tile += nblk) {
            int m0 = (tile % 72)*64, n0 = (tile / 72)*64;
            float4v acc[4];
            #pragma unroll
            for (int ni = 0; ni < 4; ++ni) acc[ni] = (float4v){0.f,0.f,0.f,0.f};
            for (int k0 = 0; k0 < K; k0 += 32) {
                half8 a0 = *(const half8*)(xn + (size_t)(m0 + lr)*K + k0 + lk);
                const float* bp = w_qkv + (size_t)(n0 + lr)*K + k0 + lk;
                float4 b0 = *(const float4*)bp;
                float4 b1 = *(const float4*)(bp + 4);
                half8 hb;
                hb[0]=(_Float16)b0.x; hb[1]=(_Float16)b0.y; hb[2]=(_Float16)b0.z; hb[3]=(_Float16)b0.w;
                hb[4]=(_Float16)b1.x; hb[5]=(_Float16)b1.y; hb[6]=(_Float16)b1.z; hb[7]=(_Float16)b1.w;
                __syncthreads();
                *(half8*)&sm.g.As[lr*LDT + lk] = a0;
                *(half8*)&sm.g.Bs[lr*LDT + lk] = hb;
                __syncthreads();
                half8 af = *(const half8*)&sm.g.As[(wave*16 + frow)*LDT + kq];
                #pragma unroll
                for (int ni = 0; ni < 4; ++ni) {
                    half8 bf = *(const half8*)&sm.g.Bs[(ni*16 + frow)*LDT + kq];
                    acc[ni] = __builtin_amdgcn_mfma_f32_16x16x32_f16(af, bf, acc[ni], 0, 0, 0);
                }
            }
            int sel  = n0 >> 8;
            int head = (n0 >> 6) & 3;
            _Float16* outp = (sel == 0) ? qh : (sel == 1) ? kh : vh;
            #pragma unroll
            for (int r = 0; r < 4; ++r) {
                int pix = m0 + wave*16 + rbase + r;
                float v0 = acc[0][r], v1 = acc[1][r], v2 = acc[2][r], v3 = acc[3][r];
                if (sel < 2) {
                    int hw = pix % (HH*WW);
                    float p = (col < 8) ? pos[hw*2] : pos[hw*2+1];
                    float sn, cs;
                    __sincosf(p*freq, &sn, &cs);
                    float o0 = v0*cs - v1*sn;
                    float o1 = v1*cs + v0*sn;
                    v0 = o0; v1 = o1;
                    if (sel == 0) { v0*=0.125f; v1*=0.125f; v2*=0.125f; v3*=0.125f; }
                }
                size_t base = (size_t)pix*DM + head*EH;
                outp[base +  0 + col] = (_Float16)v0;
                outp[base + 16 + col] = (_Float16)v1;
                outp[base + 32 + col] = (_Float16)v2;
                outp[base + 48 + col] = (_Float16)v3;
            }
            __syncthreads();   // protect LDS for next tile
        }
    }
    GBAR(2);

    // ================= Phase 3: MFMA neighborhood attention (288 tiles) =================
    {
        int col = lane & 15, quad = lane >> 4;
        for (int tile = bid; tile < 36*N_B*NH; tile += nblk) {
            int bx = tile % 36, by = tile / 36;
            int ty = bx / 6, tx = bx % 6;
            int b = by >> 2, head = by & 3;
            int qh0 = ty*8, qw0 = tx*8;
            int rh0 = min(max(qh0-3, 0), HH-14);
            int rw0 = min(max(qw0-3, 0), WW-14);

            {
                int nbl = t & 31;
                int e0  = (t >> 5) * 8;
                #pragma unroll
                for (int pass = 0; pass < 7; ++pass) {
                    int nb = pass*32 + nbl;
                    int nr = nb >> 4, nc = nb & 15;
                    int pix = (b*HH + rh0+nr)*WW + rw0 + nc;
                    half8 vv = *(const half8*)(vh + (size_t)pix*DM + head*EH + e0);
                    #pragma unroll
                    for (int i = 0; i < 8; ++i)
                        sm.at.VT[(e0+i)*232 + nb] = vv[i];
                }
            }

            int qidx_a = wave*16 + col;
            int pixq = (b*HH + qh0 + (qidx_a>>3))*WW + qw0 + (qidx_a & 7);
            const _Float16* qp = qh + (size_t)pixq*DM + head*EH;
            half8 qf0 = *(const half8*)(qp + quad*8);
            half8 qf1 = *(const half8*)(qp + 32 + quad*8);

            float4v s[14];
            #pragma unroll
            for (int nr = 0; nr < 14; ++nr) {
                int pixk = (b*HH + rh0+nr)*WW + rw0 + col;
                const _Float16* kp = kh + (size_t)pixk*DM + head*EH;
                half8 kf0 = *(const half8*)(kp + quad*8);
                half8 kf1 = *(const half8*)(kp + 32 + quad*8);
                float4v a = (float4v){0.f,0.f,0.f,0.f};
                a = __builtin_amdgcn_mfma_f32_16x16x32_f16(qf0, kf0, a, 0, 0, 0);
                a = __builtin_amdgcn_mfma_f32_16x16x32_f16(qf1, kf1, a, 0, 0, 0);
                s[nr] = a;
            }

            int sh_[4], uw_[4];
            #pragma unroll
            for (int r = 0; r < 4; ++r) {
                int qidx = wave*16 + quad*4 + r;
                int qhh = qh0 + (qidx>>3), qww = qw0 + (qidx & 7);
                sh_[r] = min(max(qhh-3, 0), HH-KS);
                int sw_ = min(max(qww-3, 0), WW-KS);
                uw_[r] = rw0 + col - sw_;
            }
            #pragma unroll
            for (int nr = 0; nr < 14; ++nr)
                #pragma unroll
                for (int r = 0; r < 4; ++r) {
                    int uh = rh0 + nr - sh_[r];
                    bool ok = ((unsigned)uh < 7u) && ((unsigned)uw_[r] < 7u);
                    s[nr][r] = ok ? s[nr][r] : -1e30f;
                }
            #pragma unroll
            for (int r = 0; r < 4; ++r) {
                float m = s[0][r];
                #pragma unroll
                for (int nr = 1; nr < 14; ++nr) m = fmaxf(m, s[nr][r]);
                m = fmaxf(m, __shfl_xor(m, 1, 64));
                m = fmaxf(m, __shfl_xor(m, 2, 64));
                m = fmaxf(m, __shfl_xor(m, 4, 64));
                m = fmaxf(m, __shfl_xor(m, 8, 64));
                float sum = 0.f;
                #pragma unroll
                for (int nr = 0; nr < 14; ++nr) { float p = __expf(s[nr][r] - m); s[nr][r] = p; sum += p; }
                sum += __shfl_xor(sum, 1, 64);
                sum += __shfl_xor(sum, 2, 64);
                sum += __shfl_xor(sum, 4, 64);
                sum += __shfl_xor(sum, 8, 64);
                float rs = 1.f / sum;
                #pragma unroll
                for (int nr = 0; nr < 14; ++nr)
                    sm.at.SP[(wave*16 + quad*4 + r)*232 + nr*16 + col] = (_Float16)(s[nr][r] * rs);
            }
            __syncthreads();

            float4v o[4];
            #pragma unroll
            for (int dt = 0; dt < 4; ++dt) o[dt] = (float4v){0.f,0.f,0.f,0.f};
            #pragma unroll
            for (int ks = 0; ks < 7; ++ks) {
                half8 pa = *(const half8*)&sm.at.SP[(wave*16 + col)*232 + ks*32 + quad*8];
                #pragma unroll
                for (int dt = 0; dt < 4; ++dt) {
                    half8 vf = *(const half8*)&sm.at.VT[(dt*16 + col)*232 + ks*32 + quad*8];
                    o[dt] = __builtin_amdgcn_mfma_f32_16x16x32_f16(pa, vf, o[dt], 0, 0, 0);
                }
            }
            #pragma unroll
            for (int r = 0; r < 4; ++r) {
                int qidx = wave*16 + quad*4 + r;
                int pix = (b*HH + qh0 + (qidx>>3))*WW + qw0 + (qidx & 7);
                #pragma unroll
                for (int dt = 0; dt < 4; ++dt)
                    obuf[(size_t)pix*DM + head*EH + dt*16 + col] = (_Float16)o[dt][r];
            }
            __syncthreads();   // protect VT/SP for next tile
        }
    }
    GBAR(3);

    // ================= Phase 4: out GEMM C = obuf @ w_out^T + skip (288 tiles) =================
    {
        const int K = DM, N = DM, LDT = 40;
        int lr = t >> 2, lk = (t & 3) * 8;
        int frow = lane & 15, kq = (lane >> 4) * 8;
        int col = lane & 15, rbase = (lane >> 4) * 4;
        for (int tile = bid; tile < 72*4; tile += nblk) {
            int m0 = (tile % 72)*64, n0 = (tile / 72)*64;
            float4v acc[4];
            #pragma unroll
            for (int ni = 0; ni < 4; ++ni) acc[ni] = (float4v){0.f,0.f,0.f,0.f};
            for (int k0 = 0; k0 < K; k0 += 32) {
                half8 a0 = *(const half8*)(obuf + (size_t)(m0 + lr)*K + k0 + lk);
                const float* bp = w_out + (size_t)(n0 + lr)*K + k0 + lk;
                float4 b0 = *(const float4*)bp;
                float4 b1 = *(const float4*)(bp + 4);
                half8 hb;
                hb[0]=(_Float16)b0.x; hb[1]=(_Float16)b0.y; hb[2]=(_Float16)b0.z; hb[3]=(_Float16)b0.w;
                hb[4]=(_Float16)b1.x; hb[5]=(_Float16)b1.y; hb[6]=(_Float16)b1.z; hb[7]=(_Float16)b1.w;
                __syncthreads();
                *(half8*)&sm.g.As[lr*LDT + lk] = a0;
                *(half8*)&sm.g.Bs[lr*LDT + lk] = hb;
                __syncthreads();
                half8 af = *(const half8*)&sm.g.As[(wave*16 + frow)*LDT + kq];
                #pragma unroll
                for (int ni = 0; ni < 4; ++ni) {
                    half8 bf = *(const half8*)&sm.g.Bs[(ni*16 + frow)*LDT + kq];
                    acc[ni] = __builtin_amdgcn_mfma_f32_16x16x32_f16(af, bf, acc[ni], 0, 0, 0);
                }
            }
            #pragma unroll
            for (int ni = 0; ni < 4; ++ni) {
                #pragma unroll
                for (int r = 0; r < 4; ++r) {
                    int rowg = m0 + wave*16 + rbase + r;
                    int c    = n0 + ni*16 + col;
                    out[(size_t)rowg*N + c] = acc[ni][r] + x[(size_t)rowg*N + c];
                }
            }
            __syncthreads();
        }
    }
}

extern "C" void kernel_launch(void* const* d_in, const int* in_sizes, int n_in,
                              void* d_out, int out_size, void* d_ws, size_t ws_size,
                              hipStream_t stream) {
    const float* x      = (const float*)d_in[0];
    const float* pos    = (const float*)d_in[1];
    const float* cond   = (const float*)d_in[2];
    const float* w_norm = (const float*)d_in[3];
    const float* w_qkv  = (const float*)d_in[4];
    const float* w_out  = (const float*)d_in[5];
    float* out = (float*)d_out;
    char* base = (char*)d_ws;

    const size_t SZH = (size_t)NPIX*DM*2;   // fp16 [pix][256]: 2,359,296 B
    const size_t PAD = 4096;                // attn edge reads overrun <=2 pixels
    int*      cnt    = (int*)base;                          // 64 B, zeroed each call below
    float*    scale  = (float*)(base + 256);                // 2 KB (inside the first PAD region)
    _Float16* xn_h   = (_Float16*)(base + PAD + 0*(SZH+PAD));
    _Float16* qh     = (_Float16*)(base + PAD + 1*(SZH+PAD));
    _Float16* kh     = (_Float16*)(base + PAD + 2*(SZH+PAD));
    _Float16* vh     = (_Float16*)(base + PAD + 3*(SZH+PAD));
    _Float16* obuf_h = (_Float16*)(base + PAD + 4*(SZH+PAD));

    hipMemsetAsync(cnt, 0, 64, stream);     // barrier counters (graph-capturable memset node)
    mega<<<dim3(GRID), dim3(256), 0, stream>>>(x, pos, cond, w_norm, w_qkv, w_out, out,
                                               cnt, scale, xn_h, qh, kh, vh, obuf_h);
}

// Round 9
// 263.616 us; speedup vs baseline: 1.5569x; 1.5569x over previous
//
#include <hip/hip_runtime.h>
#include <math.h>

#define N_B 2
#define HH 48
#define WW 48
#define DM 256
#define NH 4
#define EH 64
#define KS 7
#define NPIX (N_B*HH*WW)    // 4608
#define GRID 512            // 2 blocks/CU x 256 CUs; LDS 59.4KB caps HW at 2/CU (validated R8: occupancy 25%)

typedef _Float16 half8 __attribute__((ext_vector_type(8)));
typedef float float4v __attribute__((ext_vector_type(4)));

// Software global barrier. R8 post-mortem: spinning on ACQUIRE loads emits a cache-wide
// buffer_inv per poll -> continuous L2 thrash (371us, VALUBusy 1.2%). Fix: release-add once,
// RELAXED polls (coherence-point reads, no invalidates), ONE threadfence (wb+inv) on exit.
// Thread 0's fence covers the block: same CU L1 / same XCD L2, then __syncthreads orders it.
#define GBAR(idx) do { \
    __syncthreads(); \
    if (t == 0) { \
        __hip_atomic_fetch_add(&cnt[idx], 1, __ATOMIC_RELEASE, __HIP_MEMORY_SCOPE_AGENT); \
        while (__hip_atomic_load(&cnt[idx], __ATOMIC_RELAXED, __HIP_MEMORY_SCOPE_AGENT) < GRID) \
            __builtin_amdgcn_s_sleep(2); \
        __threadfence(); \
    } \
    __syncthreads(); \
} while (0)

__global__ __launch_bounds__(256, 2) void mega(const float* __restrict__ x,
                                               const float* __restrict__ pos,
                                               const float* __restrict__ cond,
                                               const float* __restrict__ w_norm,
                                               const float* __restrict__ w_qkv,
                                               const float* __restrict__ w_out,
                                               float* __restrict__ out,
                                               int* __restrict__ cnt,
                                               float* __restrict__ scale,
                                               _Float16* __restrict__ xn,
                                               _Float16* __restrict__ qh,
                                               _Float16* __restrict__ kh,
                                               _Float16* __restrict__ vh,
                                               _Float16* __restrict__ obuf) {
    int bid = blockIdx.x, nblk = gridDim.x;
    int t = threadIdx.x;
    int wave = t >> 6, lane = t & 63;

    __shared__ union {
        struct { _Float16 As[64*40]; _Float16 Bs[64*40]; } g;          // gemm phases (10 KB)
        struct { _Float16 VT[64*232]; _Float16 SP[64*232]; } at;       // attn phase (59.4 KB)
        float wsum[4];                                                  // rmsnorm phase
    } sm;

    // ================= Phase 0: scale = cond @ w_norm.T + 1 (blocks 0..15) =================
    if (bid < 16) {
        int b = bid & 1, yg = bid >> 1;
        int d = yg*32 + wave*8 + (lane >> 3);
        int l8 = lane & 7;
        const float4* wr4 = (const float4*)(w_norm + (size_t)d*DM) + l8*8;
        const float4* c4  = (const float4*)(cond + (size_t)b*DM) + l8*8;
        float acc = 0.f;
        #pragma unroll
        for (int j = 0; j < 8; ++j) {
            float4 w = wr4[j], c = c4[j];
            acc += w.x*c.x + w.y*c.y + w.z*c.z + w.w*c.w;
        }
        acc += __shfl_xor(acc, 1, 64);
        acc += __shfl_xor(acc, 2, 64);
        acc += __shfl_xor(acc, 4, 64);
        if (l8 == 0) scale[b*DM + d] = acc + 1.0f;
    }
    GBAR(0);

    // ================= Phase 1: RMSNorm -> fp16 xn =================
    for (int pix = bid; pix < NPIX; pix += nblk) {
        int b = pix / (HH*WW);
        float v = x[(size_t)pix*DM + t];
        float ss = v*v;
        #pragma unroll
        for (int off = 32; off > 0; off >>= 1) ss += __shfl_xor(ss, off, 64);
        if ((t & 63) == 0) sm.wsum[t>>6] = ss;
        __syncthreads();
        float tot = sm.wsum[0]+sm.wsum[1]+sm.wsum[2]+sm.wsum[3];
        float r = rsqrtf(tot*(1.0f/DM) + 1e-6f);
        xn[(size_t)pix*DM + t] = (_Float16)(v * scale[b*DM + t] * r);
        __syncthreads();   // protect wsum for next loop iter
    }
    GBAR(1);

    // ================= Phase 2: QKV GEMM (fp16 MFMA) + fused RoPE (864 tiles) =================
    {
        const int K = DM, LDT = 40;
        int lr = t >> 2, lk = (t & 3) * 8;
        int frow = lane & 15, kq = (lane >> 4) * 8;
        int col = lane & 15, rbase = (lane >> 4) * 4;
        float freq = __expf(1.14472988585f + (float)(col & 7) * 0.287823136624f); // pi * 10^(mf/8)
        for (int tile = bid; tile < 72*12; tile += nblk) {
            int m0 = (tile % 72)*64, n0 = (tile / 72)*64;
            float4v acc[4];
            #pragma unroll
            for (int ni = 0; ni < 4; ++ni) acc[ni] = (float4v){0.f,0.f,0.f,0.f};
            for (int k0 = 0; k0 < K; k0 += 32) {
                half8 a0 = *(const half8*)(xn + (size_t)(m0 + lr)*K + k0 + lk);
                const float* bp = w_qkv + (size_t)(n0 + lr)*K + k0 + lk;
                float4 b0 = *(const float4*)bp;
                float4 b1 = *(const float4*)(bp + 4);
                half8 hb;
                hb[0]=(_Float16)b0.x; hb[1]=(_Float16)b0.y; hb[2]=(_Float16)b0.z; hb[3]=(_Float16)b0.w;
                hb[4]=(_Float16)b1.x; hb[5]=(_Float16)b1.y; hb[6]=(_Float16)b1.z; hb[7]=(_Float16)b1.w;
                __syncthreads();
                *(half8*)&sm.g.As[lr*LDT + lk] = a0;
                *(half8*)&sm.g.Bs[lr*LDT + lk] = hb;
                __syncthreads();
                half8 af = *(const half8*)&sm.g.As[(wave*16 + frow)*LDT + kq];
                #pragma unroll
                for (int ni = 0; ni < 4; ++ni) {
                    half8 bf = *(const half8*)&sm.g.Bs[(ni*16 + frow)*LDT + kq];
                    acc[ni] = __builtin_amdgcn_mfma_f32_16x16x32_f16(af, bf, acc[ni], 0, 0, 0);
                }
            }
            int sel  = n0 >> 8;
            int head = (n0 >> 6) & 3;
            _Float16* outp = (sel == 0) ? qh : (sel == 1) ? kh : vh;
            #pragma unroll
            for (int r = 0; r < 4; ++r) {
                int pix = m0 + wave*16 + rbase + r;
                float v0 = acc[0][r], v1 = acc[1][r], v2 = acc[2][r], v3 = acc[3][r];
                if (sel < 2) {
                    int hw = pix % (HH*WW);
                    float p = (col < 8) ? pos[hw*2] : pos[hw*2+1];
                    float sn, cs;
                    __sincosf(p*freq, &sn, &cs);
                    float o0 = v0*cs - v1*sn;
                    float o1 = v1*cs + v0*sn;
                    v0 = o0; v1 = o1;
                    if (sel == 0) { v0*=0.125f; v1*=0.125f; v2*=0.125f; v3*=0.125f; }
                }
                size_t base = (size_t)pix*DM + head*EH;
                outp[base +  0 + col] = (_Float16)v0;
                outp[base + 16 + col] = (_Float16)v1;
                outp[base + 32 + col] = (_Float16)v2;
                outp[base + 48 + col] = (_Float16)v3;
            }
            __syncthreads();   // protect LDS for next tile
        }
    }
    GBAR(2);

    // ================= Phase 3: MFMA neighborhood attention (288 tiles) =================
    {
        int col = lane & 15, quad = lane >> 4;
        for (int tile = bid; tile < 36*N_B*NH; tile += nblk) {
            int bx = tile % 36, by = tile / 36;
            int ty = bx / 6, tx = bx % 6;
            int b = by >> 2, head = by & 3;
            int qh0 = ty*8, qw0 = tx*8;
            int rh0 = min(max(qh0-3, 0), HH-14);
            int rw0 = min(max(qw0-3, 0), WW-14);

            {
                int nbl = t & 31;
                int e0  = (t >> 5) * 8;
                #pragma unroll
                for (int pass = 0; pass < 7; ++pass) {
                    int nb = pass*32 + nbl;
                    int nr = nb >> 4, nc = nb & 15;
                    int pix = (b*HH + rh0+nr)*WW + rw0 + nc;
                    half8 vv = *(const half8*)(vh + (size_t)pix*DM + head*EH + e0);
                    #pragma unroll
                    for (int i = 0; i < 8; ++i)
                        sm.at.VT[(e0+i)*232 + nb] = vv[i];
                }
            }

            int qidx_a = wave*16 + col;
            int pixq = (b*HH + qh0 + (qidx_a>>3))*WW + qw0 + (qidx_a & 7);
            const _Float16* qp = qh + (size_t)pixq*DM + head*EH;
            half8 qf0 = *(const half8*)(qp + quad*8);
            half8 qf1 = *(const half8*)(qp + 32 + quad*8);

            float4v s[14];
            #pragma unroll
            for (int nr = 0; nr < 14; ++nr) {
                int pixk = (b*HH + rh0+nr)*WW + rw0 + col;
                const _Float16* kp = kh + (size_t)pixk*DM + head*EH;
                half8 kf0 = *(const half8*)(kp + quad*8);
                half8 kf1 = *(const half8*)(kp + 32 + quad*8);
                float4v a = (float4v){0.f,0.f,0.f,0.f};
                a = __builtin_amdgcn_mfma_f32_16x16x32_f16(qf0, kf0, a, 0, 0, 0);
                a = __builtin_amdgcn_mfma_f32_16x16x32_f16(qf1, kf1, a, 0, 0, 0);
                s[nr] = a;
            }

            int sh_[4], uw_[4];
            #pragma unroll
            for (int r = 0; r < 4; ++r) {
                int qidx = wave*16 + quad*4 + r;
                int qhh = qh0 + (qidx>>3), qww = qw0 + (qidx & 7);
                sh_[r] = min(max(qhh-3, 0), HH-KS);
                int sw_ = min(max(qww-3, 0), WW-KS);
                uw_[r] = rw0 + col - sw_;
            }
            #pragma unroll
            for (int nr = 0; nr < 14; ++nr)
                #pragma unroll
                for (int r = 0; r < 4; ++r) {
                    int uh = rh0 + nr - sh_[r];
                    bool ok = ((unsigned)uh < 7u) && ((unsigned)uw_[r] < 7u);
                    s[nr][r] = ok ? s[nr][r] : -1e30f;
                }
            #pragma unroll
            for (int r = 0; r < 4; ++r) {
                float m = s[0][r];
                #pragma unroll
                for (int nr = 1; nr < 14; ++nr) m = fmaxf(m, s[nr][r]);
                m = fmaxf(m, __shfl_xor(m, 1, 64));
                m = fmaxf(m, __shfl_xor(m, 2, 64));
                m = fmaxf(m, __shfl_xor(m, 4, 64));
                m = fmaxf(m, __shfl_xor(m, 8, 64));
                float sum = 0.f;
                #pragma unroll
                for (int nr = 0; nr < 14; ++nr) { float p = __expf(s[nr][r] - m); s[nr][r] = p; sum += p; }
                sum += __shfl_xor(sum, 1, 64);
                sum += __shfl_xor(sum, 2, 64);
                sum += __shfl_xor(sum, 4, 64);
                sum += __shfl_xor(sum, 8, 64);
                float rs = 1.f / sum;
                #pragma unroll
                for (int nr = 0; nr < 14; ++nr)
                    sm.at.SP[(wave*16 + quad*4 + r)*232 + nr*16 + col] = (_Float16)(s[nr][r] * rs);
            }
            __syncthreads();

            float4v o[4];
            #pragma unroll
            for (int dt = 0; dt < 4; ++dt) o[dt] = (float4v){0.f,0.f,0.f,0.f};
            #pragma unroll
            for (int ks = 0; ks < 7; ++ks) {
                half8 pa = *(const half8*)&sm.at.SP[(wave*16 + col)*232 + ks*32 + quad*8];
                #pragma unroll
                for (int dt = 0; dt < 4; ++dt) {
                    half8 vf = *(const half8*)&sm.at.VT[(dt*16 + col)*232 + ks*32 + quad*8];
                    o[dt] = __builtin_amdgcn_mfma_f32_16x16x32_f16(pa, vf, o[dt], 0, 0, 0);
                }
            }
            #pragma unroll
            for (int r = 0; r < 4; ++r) {
                int qidx = wave*16 + quad*4 + r;
                int pix = (b*HH + qh0 + (qidx>>3))*WW + qw0 + (qidx & 7);
                #pragma unroll
                for (int dt = 0; dt < 4; ++dt)
                    obuf[(size_t)pix*DM + head*EH + dt*16 + col] = (_Float16)o[dt][r];
            }
            __syncthreads();   // protect VT/SP for next tile
        }
    }
    GBAR(3);

    // ================= Phase 4: out GEMM C = obuf @ w_out^T + skip (288 tiles) =================
    {
        const int K = DM, N = DM, LDT = 40;
        int lr = t >> 2, lk = (t & 3) * 8;
        int frow = lane & 15, kq = (lane >> 4) * 8;
        int col = lane & 15, rbase = (lane >> 4) * 4;
        for (int tile = bid; tile < 72*4; tile += nblk) {
            int m0 = (tile % 72)*64, n0 = (tile / 72)*64;
            float4v acc[4];
            #pragma unroll
            for (int ni = 0; ni < 4; ++ni) acc[ni] = (float4v){0.f,0.f,0.f,0.f};
            for (int k0 = 0; k0 < K; k0 += 32) {
                half8 a0 = *(const half8*)(obuf + (size_t)(m0 + lr)*K + k0 + lk);
                const float* bp = w_out + (size_t)(n0 + lr)*K + k0 + lk;
                float4 b0 = *(const float4*)bp;
                float4 b1 = *(const float4*)(bp + 4);
                half8 hb;
                hb[0]=(_Float16)b0.x; hb[1]=(_Float16)b0.y; hb[2]=(_Float16)b0.z; hb[3]=(_Float16)b0.w;
                hb[4]=(_Float16)b1.x; hb[5]=(_Float16)b1.y; hb[6]=(_Float16)b1.z; hb[7]=(_Float16)b1.w;
                __syncthreads();
                *(half8*)&sm.g.As[lr*LDT + lk] = a0;
                *(half8*)&sm.g.Bs[lr*LDT + lk] = hb;
                __syncthreads();
                half8 af = *(const half8*)&sm.g.As[(wave*16 + frow)*LDT + kq];
                #pragma unroll
                for (int ni = 0; ni < 4; ++ni) {
                    half8 bf = *(const half8*)&sm.g.Bs[(ni*16 + frow)*LDT + kq];
                    acc[ni] = __builtin_amdgcn_mfma_f32_16x16x32_f16(af, bf, acc[ni], 0, 0, 0);
                }
            }
            #pragma unroll
            for (int ni = 0; ni < 4; ++ni) {
                #pragma unroll
                for (int r = 0; r < 4; ++r) {
                    int rowg = m0 + wave*16 + rbase + r;
                    int c    = n0 + ni*16 + col;
                    out[(size_t)rowg*N + c] = acc[ni][r] + x[(size_t)rowg*N + c];
                }
            }
            __syncthreads();
        }
    }
}

extern "C" void kernel_launch(void* const* d_in, const int* in_sizes, int n_in,
                              void* d_out, int out_size, void* d_ws, size_t ws_size,
                              hipStream_t stream) {
    const float* x      = (const float*)d_in[0];
    const float* pos    = (const float*)d_in[1];
    const float* cond   = (const float*)d_in[2];
    const float* w_norm = (const float*)d_in[3];
    const float* w_qkv  = (const float*)d_in[4];
    const float* w_out  = (const float*)d_in[5];
    float* out = (float*)d_out;
    char* base = (char*)d_ws;

    const size_t SZH = (size_t)NPIX*DM*2;   // fp16 [pix][256]: 2,359,296 B
    const size_t PAD = 4096;                // attn edge reads overrun <=2 pixels
    int*      cnt    = (int*)base;                          // 64 B, zeroed each call below
    float*    scale  = (float*)(base + 256);                // inside the first PAD region
    _Float16* xn_h   = (_Float16*)(base + PAD + 0*(SZH+PAD));
    _Float16* qh     = (_Float16*)(base + PAD + 1*(SZH+PAD));
    _Float16* kh     = (_Float16*)(base + PAD + 2*(SZH+PAD));
    _Float16* vh     = (_Float16*)(base + PAD + 3*(SZH+PAD));
    _Float16* obuf_h = (_Float16*)(base + PAD + 4*(SZH+PAD));

    hipMemsetAsync(cnt, 0, 64, stream);     // barrier counters (graph-capturable memset node)
    mega<<<dim3(GRID), dim3(256), 0, stream>>>(x, pos, cond, w_norm, w_qkv, w_out, out,
                                               cnt, scale, xn_h, qh, kh, vh, obuf_h);
}

// Round 10
// 257.836 us; speedup vs baseline: 1.5918x; 1.0224x over previous
//
#include <hip/hip_runtime.h>
#include <math.h>

#define N_B 2
#define HH 48
#define WW 48
#define DM 256
#define NH 4
#define EH 64
#define KS 7
#define NPIX (N_B*HH*WW)    // 4608
#define GRID 512            // 2 blocks/CU x 256 CUs; LDS 59.4KB caps HW at 2/CU (validated R8/R9: occupancy ~24%)

typedef _Float16 half8 __attribute__((ext_vector_type(8)));
typedef float float4v __attribute__((ext_vector_type(4)));

// Software global barrier, v3.
// R8: ACQUIRE poll -> cache-wide buffer_inv per poll -> L2 thrash (371us).
// R9: RELAXED plain-load poll -> served by non-coherent local XCD L2 -> stale line, ~53us/barrier
//     eviction-timescale exits (218us).
// Fix: poll with an atomic RMW (fetch_add 0) — RMWs always execute at the coherence point
// (proven coherent by R8/R9's releasing adds), no cache invalidation, can't read stale.
// s_sleep(32) (~0.85us) backoff keeps 512 same-line RMWs under the atomic-bank rate.
#define GBAR(idx) do { \
    __syncthreads(); \
    if (t == 0) { \
        int v_ = __hip_atomic_fetch_add(&cnt[idx], 1, __ATOMIC_RELEASE, __HIP_MEMORY_SCOPE_AGENT); \
        if (v_ < GRID-1) { \
            while (__hip_atomic_fetch_add(&cnt[idx], 0, __ATOMIC_RELAXED, __HIP_MEMORY_SCOPE_AGENT) < GRID) \
                __builtin_amdgcn_s_sleep(32); \
        } \
        __threadfence(); \
    } \
    __syncthreads(); \
} while (0)

__global__ __launch_bounds__(256, 2) void mega(const float* __restrict__ x,
                                               const float* __restrict__ pos,
                                               const float* __restrict__ cond,
                                               const float* __restrict__ w_norm,
                                               const float* __restrict__ w_qkv,
                                               const float* __restrict__ w_out,
                                               float* __restrict__ out,
                                               int* __restrict__ cnt,
                                               float* __restrict__ scale,
                                               _Float16* __restrict__ xn,
                                               _Float16* __restrict__ qh,
                                               _Float16* __restrict__ kh,
                                               _Float16* __restrict__ vh,
                                               _Float16* __restrict__ obuf) {
    int bid = blockIdx.x, nblk = gridDim.x;
    int t = threadIdx.x;
    int wave = t >> 6, lane = t & 63;

    __shared__ union {
        struct { _Float16 As[64*40]; _Float16 Bs[64*40]; } g;          // gemm phases (10 KB)
        struct { _Float16 VT[64*232]; _Float16 SP[64*232]; } at;       // attn phase (59.4 KB)
        float wsum[4];                                                  // rmsnorm phase
    } sm;

    // ================= Phase 0: scale = cond @ w_norm.T + 1 (blocks 0..15) =================
    if (bid < 16) {
        int b = bid & 1, yg = bid >> 1;
        int d = yg*32 + wave*8 + (lane >> 3);
        int l8 = lane & 7;
        const float4* wr4 = (const float4*)(w_norm + (size_t)d*DM) + l8*8;
        const float4* c4  = (const float4*)(cond + (size_t)b*DM) + l8*8;
        float acc = 0.f;
        #pragma unroll
        for (int j = 0; j < 8; ++j) {
            float4 w = wr4[j], c = c4[j];
            acc += w.x*c.x + w.y*c.y + w.z*c.z + w.w*c.w;
        }
        acc += __shfl_xor(acc, 1, 64);
        acc += __shfl_xor(acc, 2, 64);
        acc += __shfl_xor(acc, 4, 64);
        if (l8 == 0) scale[b*DM + d] = acc + 1.0f;
    }
    GBAR(0);

    // ================= Phase 1: RMSNorm -> fp16 xn =================
    for (int pix = bid; pix < NPIX; pix += nblk) {
        int b = pix / (HH*WW);
        float v = x[(size_t)pix*DM + t];
        float ss = v*v;
        #pragma unroll
        for (int off = 32; off > 0; off >>= 1) ss += __shfl_xor(ss, off, 64);
        if ((t & 63) == 0) sm.wsum[t>>6] = ss;
        __syncthreads();
        float tot = sm.wsum[0]+sm.wsum[1]+sm.wsum[2]+sm.wsum[3];
        float r = rsqrtf(tot*(1.0f/DM) + 1e-6f);
        xn[(size_t)pix*DM + t] = (_Float16)(v * scale[b*DM + t] * r);
        __syncthreads();   // protect wsum for next loop iter
    }
    GBAR(1);

    // ================= Phase 2: QKV GEMM (fp16 MFMA) + fused RoPE (864 tiles) =================
    {
        const int K = DM, LDT = 40;
        int lr = t >> 2, lk = (t & 3) * 8;
        int frow = lane & 15, kq = (lane >> 4) * 8;
        int col = lane & 15, rbase = (lane >> 4) * 4;
        float freq = __expf(1.14472988585f + (float)(col & 7) * 0.287823136624f); // pi * 10^(mf/8)
        for (int tile = bid; tile < 72*12; tile += nblk) {
            int m0 = (tile % 72)*64, n0 = (tile / 72)*64;
            float4v acc[4];
            #pragma unroll
            for (int ni = 0; ni < 4; ++ni) acc[ni] = (float4v){0.f,0.f,0.f,0.f};
            for (int k0 = 0; k0 < K; k0 += 32) {
                half8 a0 = *(const half8*)(xn + (size_t)(m0 + lr)*K + k0 + lk);
                const float* bp = w_qkv + (size_t)(n0 + lr)*K + k0 + lk;
                float4 b0 = *(const float4*)bp;
                float4 b1 = *(const float4*)(bp + 4);
                half8 hb;
                hb[0]=(_Float16)b0.x; hb[1]=(_Float16)b0.y; hb[2]=(_Float16)b0.z; hb[3]=(_Float16)b0.w;
                hb[4]=(_Float16)b1.x; hb[5]=(_Float16)b1.y; hb[6]=(_Float16)b1.z; hb[7]=(_Float16)b1.w;
                __syncthreads();
                *(half8*)&sm.g.As[lr*LDT + lk] = a0;
                *(half8*)&sm.g.Bs[lr*LDT + lk] = hb;
                __syncthreads();
                half8 af = *(const half8*)&sm.g.As[(wave*16 + frow)*LDT + kq];
                #pragma unroll
                for (int ni = 0; ni < 4; ++ni) {
                    half8 bf = *(const half8*)&sm.g.Bs[(ni*16 + frow)*LDT + kq];
                    acc[ni] = __builtin_amdgcn_mfma_f32_16x16x32_f16(af, bf, acc[ni], 0, 0, 0);
                }
            }
            int sel  = n0 >> 8;
            int head = (n0 >> 6) & 3;
            _Float16* outp = (sel == 0) ? qh : (sel == 1) ? kh : vh;
            #pragma unroll
            for (int r = 0; r < 4; ++r) {
                int pix = m0 + wave*16 + rbase + r;
                float v0 = acc[0][r], v1 = acc[1][r], v2 = acc[2][r], v3 = acc[3][r];
                if (sel < 2) {
                    int hw = pix % (HH*WW);
                    float p = (col < 8) ? pos[hw*2] : pos[hw*2+1];
                    float sn, cs;
                    __sincosf(p*freq, &sn, &cs);
                    float o0 = v0*cs - v1*sn;
                    float o1 = v1*cs + v0*sn;
                    v0 = o0; v1 = o1;
                    if (sel == 0) { v0*=0.125f; v1*=0.125f; v2*=0.125f; v3*=0.125f; }
                }
                size_t base = (size_t)pix*DM + head*EH;
                outp[base +  0 + col] = (_Float16)v0;
                outp[base + 16 + col] = (_Float16)v1;
                outp[base + 32 + col] = (_Float16)v2;
                outp[base + 48 + col] = (_Float16)v3;
            }
            __syncthreads();   // protect LDS for next tile
        }
    }
    GBAR(2);

    // ================= Phase 3: MFMA neighborhood attention (288 tiles) =================
    {
        int col = lane & 15, quad = lane >> 4;
        for (int tile = bid; tile < 36*N_B*NH; tile += nblk) {
            int bx = tile % 36, by = tile / 36;
            int ty = bx / 6, tx = bx % 6;
            int b = by >> 2, head = by & 3;
            int qh0 = ty*8, qw0 = tx*8;
            int rh0 = min(max(qh0-3, 0), HH-14);
            int rw0 = min(max(qw0-3, 0), WW-14);

            {
                int nbl = t & 31;
                int e0  = (t >> 5) * 8;
                #pragma unroll
                for (int pass = 0; pass < 7; ++pass) {
                    int nb = pass*32 + nbl;
                    int nr = nb >> 4, nc = nb & 15;
                    int pix = (b*HH + rh0+nr)*WW + rw0 + nc;
                    half8 vv = *(const half8*)(vh + (size_t)pix*DM + head*EH + e0);
                    #pragma unroll
                    for (int i = 0; i < 8; ++i)
                        sm.at.VT[(e0+i)*232 + nb] = vv[i];
                }
            }

            int qidx_a = wave*16 + col;
            int pixq = (b*HH + qh0 + (qidx_a>>3))*WW + qw0 + (qidx_a & 7);
            const _Float16* qp = qh + (size_t)pixq*DM + head*EH;
            half8 qf0 = *(const half8*)(qp + quad*8);
            half8 qf1 = *(const half8*)(qp + 32 + quad*8);

            float4v s[14];
            #pragma unroll
            for (int nr = 0; nr < 14; ++nr) {
                int pixk = (b*HH + rh0+nr)*WW + rw0 + col;
                const _Float16* kp = kh + (size_t)pixk*DM + head*EH;
                half8 kf0 = *(const half8*)(kp + quad*8);
                half8 kf1 = *(const half8*)(kp + 32 + quad*8);
                float4v a = (float4v){0.f,0.f,0.f,0.f};
                a = __builtin_amdgcn_mfma_f32_16x16x32_f16(qf0, kf0, a, 0, 0, 0);
                a = __builtin_amdgcn_mfma_f32_16x16x32_f16(qf1, kf1, a, 0, 0, 0);
                s[nr] = a;
            }

            int sh_[4], uw_[4];
            #pragma unroll
            for (int r = 0; r < 4; ++r) {
                int qidx = wave*16 + quad*4 + r;
                int qhh = qh0 + (qidx>>3), qww = qw0 + (qidx & 7);
                sh_[r] = min(max(qhh-3, 0), HH-KS);
                int sw_ = min(max(qww-3, 0), WW-KS);
                uw_[r] = rw0 + col - sw_;
            }
            #pragma unroll
            for (int nr = 0; nr < 14; ++nr)
                #pragma unroll
                for (int r = 0; r < 4; ++r) {
                    int uh = rh0 + nr - sh_[r];
                    bool ok = ((unsigned)uh < 7u) && ((unsigned)uw_[r] < 7u);
                    s[nr][r] = ok ? s[nr][r] : -1e30f;
                }
            #pragma unroll
            for (int r = 0; r < 4; ++r) {
                float m = s[0][r];
                #pragma unroll
                for (int nr = 1; nr < 14; ++nr) m = fmaxf(m, s[nr][r]);
                m = fmaxf(m, __shfl_xor(m, 1, 64));
                m = fmaxf(m, __shfl_xor(m, 2, 64));
                m = fmaxf(m, __shfl_xor(m, 4, 64));
                m = fmaxf(m, __shfl_xor(m, 8, 64));
                float sum = 0.f;
                #pragma unroll
                for (int nr = 0; nr < 14; ++nr) { float p = __expf(s[nr][r] - m); s[nr][r] = p; sum += p; }
                sum += __shfl_xor(sum, 1, 64);
                sum += __shfl_xor(sum, 2, 64);
                sum += __shfl_xor(sum, 4, 64);
                sum += __shfl_xor(sum, 8, 64);
                float rs = 1.f / sum;
                #pragma unroll
                for (int nr = 0; nr < 14; ++nr)
                    sm.at.SP[(wave*16 + quad*4 + r)*232 + nr*16 + col] = (_Float16)(s[nr][r] * rs);
            }
            __syncthreads();

            float4v o[4];
            #pragma unroll
            for (int dt = 0; dt < 4; ++dt) o[dt] = (float4v){0.f,0.f,0.f,0.f};
            #pragma unroll
            for (int ks = 0; ks < 7; ++ks) {
                half8 pa = *(const half8*)&sm.at.SP[(wave*16 + col)*232 + ks*32 + quad*8];
                #pragma unroll
                for (int dt = 0; dt < 4; ++dt) {
                    half8 vf = *(const half8*)&sm.at.VT[(dt*16 + col)*232 + ks*32 + quad*8];
                    o[dt] = __builtin_amdgcn_mfma_f32_16x16x32_f16(pa, vf, o[dt], 0, 0, 0);
                }
            }
            #pragma unroll
            for (int r = 0; r < 4; ++r) {
                int qidx = wave*16 + quad*4 + r;
                int pix = (b*HH + qh0 + (qidx>>3))*WW + qw0 + (qidx & 7);
                #pragma unroll
                for (int dt = 0; dt < 4; ++dt)
                    obuf[(size_t)pix*DM + head*EH + dt*16 + col] = (_Float16)o[dt][r];
            }
            __syncthreads();   // protect VT/SP for next tile
        }
    }
    GBAR(3);

    // ================= Phase 4: out GEMM C = obuf @ w_out^T + skip (288 tiles) =================
    {
        const int K = DM, N = DM, LDT = 40;
        int lr = t >> 2, lk = (t & 3) * 8;
        int frow = lane & 15, kq = (lane >> 4) * 8;
        int col = lane & 15, rbase = (lane >> 4) * 4;
        for (int tile = bid; tile < 72*4; tile += nblk) {
            int m0 = (tile % 72)*64, n0 = (tile / 72)*64;
            float4v acc[4];
            #pragma unroll
            for (int ni = 0; ni < 4; ++ni) acc[ni] = (float4v){0.f,0.f,0.f,0.f};
            for (int k0 = 0; k0 < K; k0 += 32) {
                half8 a0 = *(const half8*)(obuf + (size_t)(m0 + lr)*K + k0 + lk);
                const float* bp = w_out + (size_t)(n0 + lr)*K + k0 + lk;
                float4 b0 = *(const float4*)bp;
                float4 b1 = *(const float4*)(bp + 4);
                half8 hb;
                hb[0]=(_Float16)b0.x; hb[1]=(_Float16)b0.y; hb[2]=(_Float16)b0.z; hb[3]=(_Float16)b0.w;
                hb[4]=(_Float16)b1.x; hb[5]=(_Float16)b1.y; hb[6]=(_Float16)b1.z; hb[7]=(_Float16)b1.w;
                __syncthreads();
                *(half8*)&sm.g.As[lr*LDT + lk] = a0;
                *(half8*)&sm.g.Bs[lr*LDT + lk] = hb;
                __syncthreads();
                half8 af = *(const half8*)&sm.g.As[(wave*16 + frow)*LDT + kq];
                #pragma unroll
                for (int ni = 0; ni < 4; ++ni) {
                    half8 bf = *(const half8*)&sm.g.Bs[(ni*16 + frow)*LDT + kq];
                    acc[ni] = __builtin_amdgcn_mfma_f32_16x16x32_f16(af, bf, acc[ni], 0, 0, 0);
                }
            }
            #pragma unroll
            for (int ni = 0; ni < 4; ++ni) {
                #pragma unroll
                for (int r = 0; r < 4; ++r) {
                    int rowg = m0 + wave*16 + rbase + r;
                    int c    = n0 + ni*16 + col;
                    out[(size_t)rowg*N + c] = acc[ni][r] + x[(size_t)rowg*N + c];
                }
            }
            __syncthreads();
        }
    }
}

extern "C" void kernel_launch(void* const* d_in, const int* in_sizes, int n_in,
                              void* d_out, int out_size, void* d_ws, size_t ws_size,
                              hipStream_t stream) {
    const float* x      = (const float*)d_in[0];
    const float* pos    = (const float*)d_in[1];
    const float* cond   = (const float*)d_in[2];
    const float* w_norm = (const float*)d_in[3];
    const float* w_qkv  = (const float*)d_in[4];
    const float* w_out  = (const float*)d_in[5];
    float* out = (float*)d_out;
    char* base = (char*)d_ws;

    const size_t SZH = (size_t)NPIX*DM*2;   // fp16 [pix][256]: 2,359,296 B
    const size_t PAD = 4096;                // attn edge reads overrun <=2 pixels
    int*      cnt    = (int*)base;                          // 64 B, zeroed each call below
    float*    scale  = (float*)(base + 256);                // inside the first PAD region
    _Float16* xn_h   = (_Float16*)(base + PAD + 0*(SZH+PAD));
    _Float16* qh     = (_Float16*)(base + PAD + 1*(SZH+PAD));
    _Float16* kh     = (_Float16*)(base + PAD + 2*(SZH+PAD));
    _Float16* vh     = (_Float16*)(base + PAD + 3*(SZH+PAD));
    _Float16* obuf_h = (_Float16*)(base + PAD + 4*(SZH+PAD));

    hipMemsetAsync(cnt, 0, 64, stream);     // barrier counters (graph-capturable memset node)
    mega<<<dim3(GRID), dim3(256), 0, stream>>>(x, pos, cond, w_norm, w_qkv, w_out, out,
                                               cnt, scale, xn_h, qh, kh, vh, obuf_h);
}